// Round 1
// baseline (264.845 us; speedup 1.0000x reference)
//
#include <hip/hip_runtime.h>
#include <hip/hip_bf16.h>

#define N_NODES 1536
#define NF 64
#define NOUT 64
#define FIN 65

typedef __bf16 bf16x8 __attribute__((ext_vector_type(8)));
typedef float f32x4 __attribute__((ext_vector_type(4)));

// One block: one row i, 128 columns j. 4 waves x (2 M-frags x 4 N-frags) of
// v_mfma_f32_16x16x32_bf16. No LDS: feat (384 KB) and W (16.6 KB) are
// L1/L2/L3-resident; the kernel is bound by the 604 MB output stream.
__global__ __launch_bounds__(256, 2)
void edge_gcn_mfma(const float* __restrict__ feat,
                   const float* __restrict__ adj,
                   const float* __restrict__ W,
                   const float* __restrict__ b,
                   float* __restrict__ out)
{
    const int tid  = threadIdx.x;
    const int lane = tid & 63;
    const int wv   = tid >> 6;          // wave 0..3
    const int l15  = lane & 15;
    const int lg   = lane >> 4;         // 0..3

    const int i  = blockIdx.y;
    const int j0 = blockIdx.x * 128;
    const int jw = j0 + wv * 32;        // this wave's 32 output rows

    // ---- B fragments: B[k][col] = W[col][k]; col = n*16+l15, k = kk*32+lg*8+e
    bf16x8 bfrag[2][4];
#pragma unroll
    for (int kk = 0; kk < 2; ++kk) {
#pragma unroll
        for (int n = 0; n < 4; ++n) {
            const float* wp = W + (n * 16 + l15) * FIN + kk * 32 + lg * 8;
#pragma unroll
            for (int e = 0; e < 8; ++e) bfrag[kk][n][e] = (__bf16)wp[e];
        }
    }

    // ---- feat[i] slices this lane needs (same k map as A frags) ----
    float fi[2][8];
#pragma unroll
    for (int kk = 0; kk < 2; ++kk) {
        const float* fp = feat + i * NF + kk * 32 + lg * 8;
#pragma unroll
        for (int e = 0; e < 8; ++e) fi[kk][e] = fp[e];
    }

    f32x4 acc[2][4];
#pragma unroll
    for (int m = 0; m < 2; ++m)
#pragma unroll
        for (int n = 0; n < 4; ++n)
            acc[m][n] = (f32x4){0.f, 0.f, 0.f, 0.f};

    // ---- main MFMA: A[row][k] = |feat[j][k] - feat[i][k]|, row = l15 ----
#pragma unroll
    for (int m = 0; m < 2; ++m) {
        const int j = jw + m * 16 + l15;
        const float* fjrow = feat + j * NF;
#pragma unroll
        for (int kk = 0; kk < 2; ++kk) {
            const float* fj = fjrow + kk * 32 + lg * 8;
            bf16x8 afrag;
#pragma unroll
            for (int e = 0; e < 8; ++e)
                afrag[e] = (__bf16)fabsf(fj[e] - fi[kk][e]);
#pragma unroll
            for (int n = 0; n < 4; ++n)
                acc[m][n] = __builtin_amdgcn_mfma_f32_16x16x32_bf16(
                    afrag, bfrag[kk][n], acc[m][n], 0, 0, 0);
        }
    }

    // ---- epilogue: + adj[i][j]*W[:,64] + b, exact f32 ----
    float wl[4], bv[4];
#pragma unroll
    for (int n = 0; n < 4; ++n) {
        wl[n] = W[(n * 16 + l15) * FIN + NF];
        bv[n] = b[n * 16 + l15];
    }

#pragma unroll
    for (int m = 0; m < 2; ++m) {
#pragma unroll
        for (int r = 0; r < 4; ++r) {
            const int j = jw + m * 16 + lg * 4 + r;   // C/D row = lg*4+r
            const float av = adj[(size_t)i * N_NODES + j];
            float* op = out + ((size_t)i * N_NODES + j) * NOUT;
#pragma unroll
            for (int n = 0; n < 4; ++n)
                op[n * 16 + l15] = acc[m][n][r] + av * wl[n] + bv[n];
        }
    }
}

extern "C" void kernel_launch(void* const* d_in, const int* in_sizes, int n_in,
                              void* d_out, int out_size, void* d_ws, size_t ws_size,
                              hipStream_t stream) {
    const float* feat = (const float*)d_in[0];   // [1536][64]
    const float* adj  = (const float*)d_in[1];   // [1536][1536]
    const float* W    = (const float*)d_in[2];   // [64][65]
    const float* b    = (const float*)d_in[3];   // [64]
    float* out = (float*)d_out;                  // [1536*1536][64]

    dim3 grid(N_NODES / 128, N_NODES);
    dim3 block(256);
    edge_gcn_mfma<<<grid, block, 0, stream>>>(feat, adj, W, b, out);
}